// Round 9
// baseline (630.477 us; speedup 1.0000x reference)
//
#include <hip/hip_runtime.h>
#include <hip/hip_bf16.h>

#define N_NODES 100000
#define N_EDGES 800000
#define DD 128
#define TILE 32
#define NBLK 3125         // ceil(N_NODES / 32)
#define NSCAN1 391        // ceil(N_NODES / 256)
#define EPSV 1e-5f
#define ECAP 768          // staged edge capacity per 32-node tile (mean 256)
#define PGRID 2048        // persistent grid: 8 blocks/CU x 256 CUs

typedef short bf16x8 __attribute__((ext_vector_type(8)));
typedef float f32x4 __attribute__((ext_vector_type(4)));

__device__ __forceinline__ short f2bf(float f) {
    unsigned u = __float_as_uint(f);
    unsigned r = (u + 0x7fffu + ((u >> 16) & 1u)) >> 16;  // RNE
    return (short)r;
}
__device__ __forceinline__ float bf2f(short s) {
    return __uint_as_float(((unsigned)(unsigned short)s) << 16);
}

// ---------------- setup: x fp32->bf16 fused with degree count ----------------
__global__ void k_setup(const float* __restrict__ x, short* __restrict__ xbf,
                        const int* __restrict__ dst, int* __restrict__ cnt) {
    int i = blockIdx.x * 256 + threadIdx.x;
    if (i < N_NODES * DD / 8) {
        f32x4 v0 = *(const f32x4*)(x + (size_t)i * 8);
        f32x4 v1 = *(const f32x4*)(x + (size_t)i * 8 + 4);
        bf16x8 t;
        t[0] = f2bf(v0.x); t[1] = f2bf(v0.y); t[2] = f2bf(v0.z); t[3] = f2bf(v0.w);
        t[4] = f2bf(v1.x); t[5] = f2bf(v1.y); t[6] = f2bf(v1.z); t[7] = f2bf(v1.w);
        *(bf16x8*)&xbf[(size_t)i * 8] = t;
    }
    if (i < N_EDGES) atomicAdd(&cnt[dst[i]], 1);
}

// ---------------- CSR build ----------------
__global__ void k_scan1(const int* __restrict__ cnt, int* __restrict__ off,
                        int* __restrict__ bsums) {
    __shared__ int s[256];
    int i = blockIdx.x * 256 + threadIdx.x;
    int t = threadIdx.x;
    s[t] = (i < N_NODES) ? cnt[i] : 0;
    __syncthreads();
    for (int d = 1; d < 256; d <<= 1) {
        int x = 0;
        if (t >= d) x = s[t - d];
        __syncthreads();
        s[t] += x;
        __syncthreads();
    }
    if (i < N_NODES) off[i + 1] = s[t];
    if (t == 255) bsums[blockIdx.x] = s[255];
}

__global__ void k_scan2(int* __restrict__ bsums) {
    __shared__ int s[512];
    int t = threadIdx.x;
    s[t] = (t < NSCAN1) ? bsums[t] : 0;
    __syncthreads();
    for (int d = 1; d < 512; d <<= 1) {
        int x = 0;
        if (t >= d) x = s[t - d];
        __syncthreads();
        s[t] += x;
        __syncthreads();
    }
    if (t < NSCAN1) bsums[t] = s[t];   // inclusive
}

__global__ void k_scan3(int* __restrict__ off, const int* __restrict__ bsums) {
    int i = blockIdx.x * 256 + threadIdx.x;
    int add = (blockIdx.x > 0) ? bsums[blockIdx.x - 1] : 0;
    if (i < N_NODES) off[i + 1] += add;
    if (i == 0) off[0] = 0;
}

// uses cnt (still holding counts) as a down-counter: no second memset needed
__global__ void k_fill(const int* __restrict__ src, const int* __restrict__ dst,
                       const int* __restrict__ off, int* __restrict__ cur,
                       int* __restrict__ elist) {
    int e = blockIdx.x * 256 + threadIdx.x;
    if (e < N_EDGES) {
        int d = dst[e];
        int p = atomicSub(&cur[d], 1);   // old value >= 1
        elist[off[d] + p - 1] = src[e];
    }
}

// ---------------- fold BN affine into weights/bias ----------------
__global__ void k_fold(const float* __restrict__ wl, const float* __restrict__ wr,
                       const float* __restrict__ b, const float* __restrict__ aff,
                       int use_aff,
                       short* __restrict__ wblo, short* __restrict__ wbro,
                       float* __restrict__ bias_base, float* __restrict__ bias_deg) {
    int o = blockIdx.x;     // 0..127
    int k = threadIdx.x;    // 0..127
    float a = use_aff ? aff[k] : 1.f;
    float c = use_aff ? aff[128 + k] : 0.f;
    float vl = wl[o * DD + k], vr = wr[o * DD + k];
    wblo[o * DD + k] = f2bf(vl * a);
    wbro[o * DD + k] = f2bf(vr * a);
    __shared__ float s1[128], s2[128];
    s1[k] = c * vr; s2[k] = c * vl;
    __syncthreads();
    for (int d = 64; d > 0; d >>= 1) {
        if (k < d) { s1[k] += s1[k + d]; s2[k] += s2[k + d]; }
        __syncthreads();
    }
    if (k == 0) {
        bias_base[o] = b[o] + s1[0];
        bias_deg[o] = s2[0];
    }
}

// ---------------- fused SAGE layer (persistent, dynamic tile queue) ----------
// 2048 persistent blocks (8/CU), 256 threads (4 waves). Each block pulls
// 32-node tiles from a global atomic counter until exhausted -> no grid tail,
// no inter-round bubbles. Per tile: gather (quarter-wave per row, 4-deep
// static-slot pipeline), MFMA (wave pair = 16 rows, each wave a 64-col half),
// epilogue with column stats + coalesced C write.
template <bool ELU_ON>
__global__ __launch_bounds__(256, 8) void k_sage(
    const short* __restrict__ xbf,
    const int* __restrict__ off, const int* __restrict__ elist,
    const short* __restrict__ wl, const short* __restrict__ wr,
    const float* __restrict__ bias_base, const float* __restrict__ bias_deg,
    short* __restrict__ hout, float* __restrict__ partials,
    int* __restrict__ tctr)
{
    __shared__ short agg_t[TILE * 128];   // 8KB: agg tile, then reused as C tile
    __shared__ float sstat[4 * 128];      // per-wave column stats staging
    __shared__ int soff[TILE + 1];
    __shared__ int eidx[ECAP];
    __shared__ int stile;
    const int tid = threadIdx.x;
    const int wu = __builtin_amdgcn_readfirstlane(tid >> 6);
    const int l = tid & 63;
    const int qw = l >> 4;        // quarter-wave 0..3 = row within quad
    const int ll = l & 15;        // lane in quarter-wave: cols 8*ll..8*ll+7

    for (;;) {
        if (tid == 0) stile = atomicAdd(tctr, 1);
        __syncthreads();                  // also protects LDS reuse across tiles
        const int tile = stile;
        if (tile >= NBLK) break;
        const int base = tile * TILE;

        // ---- stage offsets + edge indices into LDS ----
        if (tid < TILE + 1) soff[tid] = off[min(base + tid, N_NODES)];
        __syncthreads();
        const int ebase = soff[0];
        const int etot = soff[TILE] - ebase;
        const bool ovf = etot > ECAP;
        for (int k = tid; k < (ovf ? 0 : etot); k += 256) eidx[k] = elist[ebase + k];
        __syncthreads();
        const int* ep = ovf ? (elist + ebase) : (const int*)eidx;

        // ---- gather: each wave owns rows wu*8..wu*8+7 as 2 quads of 4 ----
#pragma unroll
        for (int q = 0; q < 2; ++q) {
            const int m = wu * 8 + q * 4 + qw;      // this quarter-wave's row
            const int ea = soff[m] - ebase;
            const int eA = soff[m + 1] - ebase;
            const int deg = eA - ea;
            float acc[8];
#pragma unroll
            for (int j = 0; j < 8; ++j) acc[j] = 0.f;

            bf16x8 v0{}, v1{}, v2{}, v3{};
            int e = ea;
#define GLOAD(sn) (*(const bf16x8*)(xbf + (size_t)(sn) * DD + 8 * ll))
            if (e < eA)     v0 = GLOAD(ep[e]);
            if (e + 1 < eA) v1 = GLOAD(ep[e + 1]);
            if (e + 2 < eA) v2 = GLOAD(ep[e + 2]);
            if (e + 3 < eA) v3 = GLOAD(ep[e + 3]);
            while (__any((int)(e < eA))) {
                if (e < eA) {
#pragma unroll
                    for (int j = 0; j < 8; ++j) acc[j] += bf2f(v0[j]);
                    if (e + 4 < eA) v0 = GLOAD(ep[e + 4]);
                }
                if (e + 1 < eA) {
#pragma unroll
                    for (int j = 0; j < 8; ++j) acc[j] += bf2f(v1[j]);
                    if (e + 5 < eA) v1 = GLOAD(ep[e + 5]);
                }
                if (e + 2 < eA) {
#pragma unroll
                    for (int j = 0; j < 8; ++j) acc[j] += bf2f(v2[j]);
                    if (e + 6 < eA) v2 = GLOAD(ep[e + 6]);
                }
                if (e + 3 < eA) {
#pragma unroll
                    for (int j = 0; j < 8; ++j) acc[j] += bf2f(v3[j]);
                    if (e + 7 < eA) v3 = GLOAD(ep[e + 7]);
                }
                e += 4;
            }
#undef GLOAD

            float inv = deg > 0 ? 1.f / (float)deg : 0.f;
            bf16x8 t;
#pragma unroll
            for (int j = 0; j < 8; ++j) t[j] = f2bf(acc[j] * inv);
            *(bf16x8*)&agg_t[m * DD + ((8 * ll) ^ ((m & 7) << 3))] = t;
        }
        __syncthreads();

        // ---- MFMA phase: wave = 16 rows (pair) x 64 cols (half) ----
        const int p = wu >> 1;
        const int half = wu & 1;
        f32x4 acc[4];
#pragma unroll
        for (int nb = 0; nb < 4; ++nb) acc[nb] = f32x4{0.f, 0.f, 0.f, 0.f};
        const int mrow = p * 16 + (l & 15);
        const int kg = (l >> 4) * 8;
        const int nloc = l & 15;
        const int groot = min(base + mrow, N_NODES - 1);
#pragma unroll
        for (int ks = 0; ks < 4; ++ks) {
            int kk = ks * 32 + kg;
            int sw = kk ^ ((mrow & 7) << 3);
            bf16x8 aa = *(const bf16x8*)&agg_t[mrow * DD + sw];
            bf16x8 ax = *(const bf16x8*)(xbf + (size_t)groot * DD + kk);
#pragma unroll
            for (int nb = 0; nb < 4; ++nb) {
                int n = half * 64 + nb * 16 + nloc;
                bf16x8 bl = *(const bf16x8*)&wl[n * DD + kk];
                bf16x8 br = *(const bf16x8*)&wr[n * DD + kk];
                acc[nb] = __builtin_amdgcn_mfma_f32_16x16x32_bf16(aa, bl, acc[nb], 0, 0, 0);
                acc[nb] = __builtin_amdgcn_mfma_f32_16x16x32_bf16(ax, br, acc[nb], 0, 0, 0);
            }
        }
        __syncthreads();   // agg tile reads done by both waves of every pair

        // ---- epilogue: bias, ELU, stats, C tile into LDS ----
        int degf[4];
#pragma unroll
        for (int r = 0; r < 4; ++r) {
            int mr_ = p * 16 + (l >> 4) * 4 + r;
            degf[r] = soff[mr_ + 1] - soff[mr_];
        }

        float colS[4], colQ[4];
#pragma unroll
        for (int nb = 0; nb < 4; ++nb) {
            int n = half * 64 + nb * 16 + nloc;
            float bb = bias_base[n];
            float bd = bias_deg[n];
            float cs = 0.f, cq = 0.f;
#pragma unroll
            for (int r = 0; r < 4; ++r) {
                int m = p * 16 + (l >> 4) * 4 + r;
                int g = base + m;
                float hv = acc[nb][r] + bb + (degf[r] > 0 ? bd : 0.f);
                if (ELU_ON) hv = hv > 0.f ? hv : expm1f(hv);
                agg_t[m * DD + (n ^ ((m & 7) << 3))] = f2bf(hv);
                float hm = (g < N_NODES) ? hv : 0.f;
                cs += hm;
                cq += hm * hm;
            }
            colS[nb] = cs; colQ[nb] = cq;
        }
#pragma unroll
        for (int nb = 0; nb < 4; ++nb) {
            colS[nb] += __shfl_xor(colS[nb], 16, 64);
            colS[nb] += __shfl_xor(colS[nb], 32, 64);
            colQ[nb] += __shfl_xor(colQ[nb], 16, 64);
            colQ[nb] += __shfl_xor(colQ[nb], 32, 64);
        }
        if (l < 16) {
#pragma unroll
            for (int nb = 0; nb < 4; ++nb) {
                sstat[wu * 128 + nb * 16 + l]      = colS[nb];
                sstat[wu * 128 + 64 + nb * 16 + l] = colQ[nb];
            }
        }
        __syncthreads();

        // ---- coalesced C write-out + stats combine ----
#pragma unroll
        for (int k = 0; k < 2; ++k) {
            int idx = (k * 256 + tid) * 8;           // short index in 32x128 tile
            int m = idx >> 7, c = idx & 127;
            int g = base + m;
            if (g < N_NODES) {
                bf16x8 v = *(const bf16x8*)&agg_t[m * DD + (c ^ ((m & 7) << 3))];
                *(bf16x8*)&hout[(size_t)g * DD + c] = v;
            }
        }
        {
            int f = tid & 127;
            int part = tid >> 7;                     // 0 = sum, 1 = sumsq
            int hsel = f >> 6;                       // which col-half wave
            int cw = part * 64 + (f & 63);
            float v = 0.f;
#pragma unroll
            for (int pr = 0; pr < 2; ++pr) v += sstat[(2 * pr + hsel) * 128 + cw];
            partials[tile * 256 + tid] = v;
        }
    }
}

// ---------------- BN stats -> affine ----------------
__global__ void k_reduce(const float* __restrict__ partials,
                         const float* __restrict__ gamma, const float* __restrict__ beta,
                         float* __restrict__ aff) {
    int f = blockIdx.x;     // 0..127
    int t = threadIdx.x;    // 256
    float s = 0.f, q = 0.f;
    for (int i = t; i < NBLK; i += 256) {
        s += partials[i * 256 + f];
        q += partials[i * 256 + 128 + f];
    }
    __shared__ float rs[256], rq[256];
    rs[t] = s; rq[t] = q;
    __syncthreads();
    for (int d = 128; d > 0; d >>= 1) {
        if (t < d) { rs[t] += rs[t + d]; rq[t] += rq[t + d]; }
        __syncthreads();
    }
    if (t == 0) {
        float mean = rs[0] / (float)N_NODES;
        float var = rq[0] / (float)N_NODES - mean * mean;
        float a = gamma[f] * rsqrtf(var + EPSV);
        aff[f] = a;
        aff[128 + f] = beta[f] - mean * a;
    }
}

// ---------------- final BN apply: bf16 h2 -> fp32 out ----------------
__global__ void k_apply(const short* __restrict__ hin, const float* __restrict__ aff,
                        float* __restrict__ out) {
    int i = blockIdx.x * 256 + threadIdx.x;  // bf16x8 units
    if (i < N_NODES * DD / 8) {
        bf16x8 v = *(const bf16x8*)(hin + (size_t)i * 8);
        int f = (i * 8) & 127;
        f32x4 a0 = *(const f32x4*)(aff + f);
        f32x4 a1 = *(const f32x4*)(aff + f + 4);
        f32x4 c0 = *(const f32x4*)(aff + 128 + f);
        f32x4 c1 = *(const f32x4*)(aff + 128 + f + 4);
        f32x4 o0, o1;
        o0.x = bf2f(v[0]) * a0.x + c0.x; o0.y = bf2f(v[1]) * a0.y + c0.y;
        o0.z = bf2f(v[2]) * a0.z + c0.z; o0.w = bf2f(v[3]) * a0.w + c0.w;
        o1.x = bf2f(v[4]) * a1.x + c1.x; o1.y = bf2f(v[5]) * a1.y + c1.y;
        o1.z = bf2f(v[6]) * a1.z + c1.z; o1.w = bf2f(v[7]) * a1.w + c1.w;
        *(f32x4*)(out + (size_t)i * 8) = o0;
        *(f32x4*)(out + (size_t)i * 8 + 4) = o1;
    }
}

extern "C" void kernel_launch(void* const* d_in, const int* in_sizes, int n_in,
                              void* d_out, int out_size, void* d_ws, size_t ws_size,
                              hipStream_t stream) {
    const float* x     = (const float*)d_in[0];
    const int*   ei    = (const int*)d_in[1];
    const float* Wl    = (const float*)d_in[2];
    const float* Wr    = (const float*)d_in[3];
    const float* b     = (const float*)d_in[4];
    const float* gamma = (const float*)d_in[5];
    const float* beta  = (const float*)d_in[6];
    float* out = (float*)d_out;

    char* ws = (char*)d_ws;
    int*   off      = (int*)(ws + 0);              // (N+1) ints
    int*   cnt      = (int*)(ws + 400128);         // N ints (count/cursor) + 3 tile ctrs
    int*   elist    = (int*)(ws + 800256);         // E ints
    int*   bsums    = (int*)(ws + 4000256);        // 512 ints
    float* partials = (float*)(ws + 4002304);      // NBLK*256 floats (3.2MB)
    float* affine   = (float*)(ws + 7202304);      // 256 floats
    short* wbl      = (short*)(ws + 7203328);      // 128*128 bf16 folded
    short* wbr      = (short*)(ws + 7236096);      // 128*128 bf16 folded
    float* biasb    = (float*)(ws + 7268864);      // 128 floats
    float* biasd    = (float*)(ws + 7269376);      // 128 floats
    short* bufA     = (short*)(ws + 7269888);      // N*D bf16: xbf, then h1
    short* bufB     = (short*)(ws + 32869888);     // N*D bf16: h0, then h2
    int*   tctr     = cnt + N_NODES;               // 3 tile counters (in cnt pad)

    const int* src = ei;
    const int* dst = ei + N_EDGES;

    // CSR build + x->bf16 (memset also zeroes the 3 tile counters)
    hipMemsetAsync(cnt, 0, (N_NODES + 3) * sizeof(int), stream);
    k_setup<<<(N_NODES * DD / 8 + 255) / 256, 256, 0, stream>>>(x, bufA, dst, cnt);
    k_scan1<<<NSCAN1, 256, 0, stream>>>(cnt, off, bsums);
    k_scan2<<<1, 512, 0, stream>>>(bsums);
    k_scan3<<<NSCAN1, 256, 0, stream>>>(off, bsums);
    k_fill<<<(N_EDGES + 255) / 256, 256, 0, stream>>>(src, dst, off, cnt, elist);

    // layer 0: xbf(bufA) -> h0 (bufB), ELU, identity affine
    k_fold<<<128, 128, 0, stream>>>(Wl, Wr, b, affine, 0, wbl, wbr, biasb, biasd);
    k_sage<true><<<PGRID, 256, 0, stream>>>(bufA, off, elist, wbl, wbr,
                                            biasb, biasd, bufB, partials, tctr);
    k_reduce<<<128, 256, 0, stream>>>(partials, gamma, beta, affine);

    // layer 1: h0(bufB) -> h1 (bufA), ELU, affine folded
    k_fold<<<128, 128, 0, stream>>>(Wl + DD * DD, Wr + DD * DD, b + DD, affine, 1,
                                    wbl, wbr, biasb, biasd);
    k_sage<true><<<PGRID, 256, 0, stream>>>(bufB, off, elist, wbl, wbr,
                                            biasb, biasd, bufA, partials, tctr + 1);
    k_reduce<<<128, 256, 0, stream>>>(partials, gamma + DD, beta + DD, affine);

    // layer 2: h1(bufA) -> h2 (bufB), no ELU, affine folded
    k_fold<<<128, 128, 0, stream>>>(Wl + 2 * DD * DD, Wr + 2 * DD * DD, b + 2 * DD,
                                    affine, 1, wbl, wbr, biasb, biasd);
    k_sage<false><<<PGRID, 256, 0, stream>>>(bufA, off, elist, wbl, wbr,
                                             biasb, biasd, bufB, partials, tctr + 2);
    k_reduce<<<128, 256, 0, stream>>>(partials, gamma + 2 * DD, beta + 2 * DD, affine);

    // final BN apply: bf16 h2 -> fp32 out
    k_apply<<<(N_NODES * DD / 8 + 255) / 256, 256, 0, stream>>>(bufB, affine, out);
}

// Round 11
// 394.533 us; speedup vs baseline: 1.5980x; 1.5980x over previous
//
#include <hip/hip_runtime.h>
#include <hip/hip_bf16.h>

#define N_NODES 100000
#define N_EDGES 800000
#define DD 128
#define TILE 32
#define NBLK 3125         // N_NODES / 32 exactly (no partial tiles)
#define NSCAN1 391        // ceil(N_NODES / 256)
#define EPSV 1e-5f
#define ECAP 768          // staged edge capacity per 32-node tile (mean 256)

typedef short bf16x8 __attribute__((ext_vector_type(8)));
typedef float f32x4 __attribute__((ext_vector_type(4)));

__device__ __forceinline__ short f2bf(float f) {
    unsigned u = __float_as_uint(f);
    unsigned r = (u + 0x7fffu + ((u >> 16) & 1u)) >> 16;  // RNE
    return (short)r;
}
__device__ __forceinline__ float bf2f(short s) {
    return __uint_as_float(((unsigned)(unsigned short)s) << 16);
}

// ------- setup: x -> bf16 + int8(row-scale) shadow, fused with degree count --
// 16 threads per row (each 8 features); row absmax via 16-lane shfl reduce.
__global__ void k_setup(const float* __restrict__ x, short* __restrict__ xbf,
                        unsigned char* __restrict__ xq, float* __restrict__ xsc,
                        const int* __restrict__ dst, int* __restrict__ cnt) {
    int i = blockIdx.x * 256 + threadIdx.x;
    if (i < N_NODES * DD / 8) {
        f32x4 v0 = *(const f32x4*)(x + (size_t)i * 8);
        f32x4 v1 = *(const f32x4*)(x + (size_t)i * 8 + 4);
        float f[8] = {v0.x, v0.y, v0.z, v0.w, v1.x, v1.y, v1.z, v1.w};
        bf16x8 t;
#pragma unroll
        for (int j = 0; j < 8; ++j) t[j] = f2bf(f[j]);
        *(bf16x8*)&xbf[(size_t)i * 8] = t;

        float mx = 0.f;
#pragma unroll
        for (int j = 0; j < 8; ++j) mx = fmaxf(mx, fabsf(f[j]));
        mx = fmaxf(mx, __shfl_xor(mx, 1, 64));
        mx = fmaxf(mx, __shfl_xor(mx, 2, 64));
        mx = fmaxf(mx, __shfl_xor(mx, 4, 64));
        mx = fmaxf(mx, __shfl_xor(mx, 8, 64));
        float qi = mx > 0.f ? 127.f / mx : 0.f;
        unsigned w0 = 0, w1 = 0;
#pragma unroll
        for (int j = 0; j < 8; ++j) {
            int u = (int)rintf(f[j] * qi) + 128;
            u = min(max(u, 0), 255);
            if (j < 4) w0 |= (unsigned)u << (8 * j);
            else       w1 |= (unsigned)u << (8 * (j - 4));
        }
        uint2 pk; pk.x = w0; pk.y = w1;
        *(uint2*)&xq[(size_t)i * 8] = pk;
        if ((i & 15) == 0) xsc[i >> 4] = mx / 127.f;
    }
    if (i < N_EDGES) atomicAdd(&cnt[dst[i]], 1);
}

// ---------------- CSR build ----------------
__global__ void k_scan1(const int* __restrict__ cnt, int* __restrict__ off,
                        int* __restrict__ bsums) {
    __shared__ int s[256];
    int i = blockIdx.x * 256 + threadIdx.x;
    int t = threadIdx.x;
    s[t] = (i < N_NODES) ? cnt[i] : 0;
    __syncthreads();
    for (int d = 1; d < 256; d <<= 1) {
        int x = 0;
        if (t >= d) x = s[t - d];
        __syncthreads();
        s[t] += x;
        __syncthreads();
    }
    if (i < N_NODES) off[i + 1] = s[t];
    if (t == 255) bsums[blockIdx.x] = s[255];
}

__global__ void k_scan2(int* __restrict__ bsums) {
    __shared__ int s[512];
    int t = threadIdx.x;
    s[t] = (t < NSCAN1) ? bsums[t] : 0;
    __syncthreads();
    for (int d = 1; d < 512; d <<= 1) {
        int x = 0;
        if (t >= d) x = s[t - d];
        __syncthreads();
        s[t] += x;
        __syncthreads();
    }
    if (t < NSCAN1) bsums[t] = s[t];   // inclusive
}

__global__ void k_scan3(int* __restrict__ off, const int* __restrict__ bsums) {
    int i = blockIdx.x * 256 + threadIdx.x;
    int add = (blockIdx.x > 0) ? bsums[blockIdx.x - 1] : 0;
    if (i < N_NODES) off[i + 1] += add;
    if (i == 0) off[0] = 0;
}

__global__ void k_fill(const int* __restrict__ src, const int* __restrict__ dst,
                       const int* __restrict__ off, int* __restrict__ cur,
                       int* __restrict__ elist) {
    int e = blockIdx.x * 256 + threadIdx.x;
    if (e < N_EDGES) {
        int d = dst[e];
        int p = atomicSub(&cur[d], 1);   // old value >= 1
        elist[off[d] + p - 1] = src[e];
    }
}

// ---------------- fold BN affine into weights/bias ----------------
__global__ void k_fold(const float* __restrict__ wl, const float* __restrict__ wr,
                       const float* __restrict__ b, const float* __restrict__ aff,
                       int use_aff,
                       short* __restrict__ wblo, short* __restrict__ wbro,
                       float* __restrict__ bias_base, float* __restrict__ bias_deg) {
    int o = blockIdx.x;     // 0..127
    int k = threadIdx.x;    // 0..127
    float a = use_aff ? aff[k] : 1.f;
    float c = use_aff ? aff[128 + k] : 0.f;
    float vl = wl[o * DD + k], vr = wr[o * DD + k];
    wblo[o * DD + k] = f2bf(vl * a);
    wbro[o * DD + k] = f2bf(vr * a);
    __shared__ float s1[128], s2[128];
    s1[k] = c * vr; s2[k] = c * vl;
    __syncthreads();
    for (int d = 64; d > 0; d >>= 1) {
        if (k < d) { s1[k] += s1[k + d]; s2[k] += s2[k + d]; }
        __syncthreads();
    }
    if (k == 0) {
        bias_base[o] = b[o] + s1[0];
        bias_deg[o] = s2[0];
    }
}

// ---------------- fused SAGE layer ----------------
// 32-node tile, 256 threads (4 waves). Gather reads the int8 shadow (128B rows
// = 2 lines/edge) with per-row scale from an L2-resident 400KB array; decode:
// acc[j] += s*byte, ssum += s, final agg = (acc - 128*ssum)/deg. Root branch
// reads bf16 from xb and the epilogue overwrites the SAME rows in place
// (gathers never touch xb -> no hazard). 4-deep static-slot load pipeline.
// MFMA: wave pair = 16 rows, each wave one 64-col half.
template <bool ELU_ON, bool WQ>
__global__ __launch_bounds__(256, 8) void k_sage(
    short* __restrict__ xb,                  // bf16: root in + h out (in place)
    const unsigned char* __restrict__ gq,    // int8 gather input
    const float* __restrict__ gsc,           // per-row scale of gq
    unsigned char* __restrict__ hq,          // int8 h out (when WQ)
    float* __restrict__ hsc,                 // per-row scale of hq (when WQ)
    const int* __restrict__ off, const int* __restrict__ elist,
    const short* __restrict__ wl, const short* __restrict__ wr,
    const float* __restrict__ bias_base, const float* __restrict__ bias_deg,
    float* __restrict__ partials)
{
    __shared__ short agg_t[TILE * 128];   // 8KB: agg tile, then reused as C tile
    __shared__ float sstat[4 * 128];      // per-wave column stats staging
    __shared__ int soff[TILE + 1];
    __shared__ int eidx[ECAP];
    const int tid = threadIdx.x;
    const int wu = __builtin_amdgcn_readfirstlane(tid >> 6);
    const int l = tid & 63;
    const int base = blockIdx.x * TILE;
    const int qw = l >> 4;        // quarter-wave 0..3 = row within quad
    const int ll = l & 15;        // lane in quarter-wave: cols 8*ll..8*ll+7

    // ---- stage offsets + edge indices into LDS ----
    if (tid < TILE + 1) soff[tid] = off[min(base + tid, N_NODES)];
    __syncthreads();
    const int ebase = soff[0];
    const int etot = soff[TILE] - ebase;
    const bool ovf = etot > ECAP;
    for (int k = tid; k < (ovf ? 0 : etot); k += 256) eidx[k] = elist[ebase + k];
    __syncthreads();
    const int* ep = ovf ? (elist + ebase) : (const int*)eidx;

    // ---- gather: each wave owns rows wu*8..wu*8+7 as 2 quads of 4 ----
#pragma unroll
    for (int q = 0; q < 2; ++q) {
        const int m = wu * 8 + q * 4 + qw;      // this quarter-wave's row
        const int ea = soff[m] - ebase;
        const int eA = soff[m + 1] - ebase;
        const int deg = eA - ea;
        float acc[8];
        float ssum = 0.f;
#pragma unroll
        for (int j = 0; j < 8; ++j) acc[j] = 0.f;

        uint2 v0{}, v1{}, v2{}, v3{};
        float s0f = 0.f, s1f = 0.f, s2f = 0.f, s3f = 0.f;
        int e = ea;
#define GLOAD(sn) (*(const uint2*)(gq + (size_t)(sn) * DD + 8 * ll))
#define ACC(v, s) { ssum += (s); \
        acc[0] += (s) * (float)((v).x & 0xffu); \
        acc[1] += (s) * (float)(((v).x >> 8) & 0xffu); \
        acc[2] += (s) * (float)(((v).x >> 16) & 0xffu); \
        acc[3] += (s) * (float)((v).x >> 24); \
        acc[4] += (s) * (float)((v).y & 0xffu); \
        acc[5] += (s) * (float)(((v).y >> 8) & 0xffu); \
        acc[6] += (s) * (float)(((v).y >> 16) & 0xffu); \
        acc[7] += (s) * (float)((v).y >> 24); }
        if (e < eA)     { int sn = ep[e];     v0 = GLOAD(sn); s0f = gsc[sn]; }
        if (e + 1 < eA) { int sn = ep[e + 1]; v1 = GLOAD(sn); s1f = gsc[sn]; }
        if (e + 2 < eA) { int sn = ep[e + 2]; v2 = GLOAD(sn); s2f = gsc[sn]; }
        if (e + 3 < eA) { int sn = ep[e + 3]; v3 = GLOAD(sn); s3f = gsc[sn]; }
        while (__any((int)(e < eA))) {
            if (e < eA) {
                ACC(v0, s0f)
                if (e + 4 < eA) { int sn = ep[e + 4]; v0 = GLOAD(sn); s0f = gsc[sn]; }
            }
            if (e + 1 < eA) {
                ACC(v1, s1f)
                if (e + 5 < eA) { int sn = ep[e + 5]; v1 = GLOAD(sn); s1f = gsc[sn]; }
            }
            if (e + 2 < eA) {
                ACC(v2, s2f)
                if (e + 6 < eA) { int sn = ep[e + 6]; v2 = GLOAD(sn); s2f = gsc[sn]; }
            }
            if (e + 3 < eA) {
                ACC(v3, s3f)
                if (e + 7 < eA) { int sn = ep[e + 7]; v3 = GLOAD(sn); s3f = gsc[sn]; }
            }
            e += 4;
        }
#undef ACC
#undef GLOAD

        float inv = deg > 0 ? 1.f / (float)deg : 0.f;
        bf16x8 t;
#pragma unroll
        for (int j = 0; j < 8; ++j) t[j] = f2bf((acc[j] - 128.f * ssum) * inv);
        *(bf16x8*)&agg_t[m * DD + ((8 * ll) ^ ((m & 7) << 3))] = t;
    }
    __syncthreads();

    // ---- MFMA phase: wave = 16 rows (pair) x 64 cols (half) ----
    const int p = wu >> 1;
    const int half = wu & 1;
    f32x4 acc[4];
#pragma unroll
    for (int nb = 0; nb < 4; ++nb) acc[nb] = f32x4{0.f, 0.f, 0.f, 0.f};
    const int mrow = p * 16 + (l & 15);
    const int kg = (l >> 4) * 8;
    const int nloc = l & 15;
    const int groot = min(base + mrow, N_NODES - 1);
#pragma unroll
    for (int ks = 0; ks < 4; ++ks) {
        int kk = ks * 32 + kg;
        int sw = kk ^ ((mrow & 7) << 3);
        bf16x8 aa = *(const bf16x8*)&agg_t[mrow * DD + sw];
        bf16x8 ax = *(const bf16x8*)(xb + (size_t)groot * DD + kk);
#pragma unroll
        for (int nb = 0; nb < 4; ++nb) {
            int n = half * 64 + nb * 16 + nloc;
            bf16x8 bl = *(const bf16x8*)&wl[n * DD + kk];
            bf16x8 br = *(const bf16x8*)&wr[n * DD + kk];
            acc[nb] = __builtin_amdgcn_mfma_f32_16x16x32_bf16(aa, bl, acc[nb], 0, 0, 0);
            acc[nb] = __builtin_amdgcn_mfma_f32_16x16x32_bf16(ax, br, acc[nb], 0, 0, 0);
        }
    }
    __syncthreads();   // agg tile reads done by both waves of every pair

    // ---- epilogue: bias, ELU, stats, C tile into LDS ----
    int degf[4];
#pragma unroll
    for (int r = 0; r < 4; ++r) {
        int mr_ = p * 16 + (l >> 4) * 4 + r;
        degf[r] = soff[mr_ + 1] - soff[mr_];
    }

    float colS[4], colQ[4];
#pragma unroll
    for (int nb = 0; nb < 4; ++nb) {
        int n = half * 64 + nb * 16 + nloc;
        float bb = bias_base[n];
        float bd = bias_deg[n];
        float cs = 0.f, cq = 0.f;
#pragma unroll
        for (int r = 0; r < 4; ++r) {
            int m = p * 16 + (l >> 4) * 4 + r;
            int g = base + m;
            float hv = acc[nb][r] + bb + (degf[r] > 0 ? bd : 0.f);
            if (ELU_ON) hv = hv > 0.f ? hv : expm1f(hv);
            agg_t[m * DD + (n ^ ((m & 7) << 3))] = f2bf(hv);
            float hm = (g < N_NODES) ? hv : 0.f;
            cs += hm;
            cq += hm * hm;
        }
        colS[nb] = cs; colQ[nb] = cq;
    }
#pragma unroll
    for (int nb = 0; nb < 4; ++nb) {
        colS[nb] += __shfl_xor(colS[nb], 16, 64);
        colS[nb] += __shfl_xor(colS[nb], 32, 64);
        colQ[nb] += __shfl_xor(colQ[nb], 16, 64);
        colQ[nb] += __shfl_xor(colQ[nb], 32, 64);
    }
    if (l < 16) {
#pragma unroll
        for (int nb = 0; nb < 4; ++nb) {
            sstat[wu * 128 + nb * 16 + l]      = colS[nb];
            sstat[wu * 128 + 64 + nb * 16 + l] = colQ[nb];
        }
    }
    __syncthreads();

    // ---- coalesced C write-out (bf16 in place + int8 shadow) + stats ----
#pragma unroll
    for (int k = 0; k < 2; ++k) {
        int idx = (k * 256 + tid) * 8;           // short index in 32x128 tile
        int m = idx >> 7, c = idx & 127;
        int g = base + m;                        // always < N_NODES (3125*32==N)
        bf16x8 v = *(const bf16x8*)&agg_t[m * DD + (c ^ ((m & 7) << 3))];
        *(bf16x8*)&xb[(size_t)g * DD + c] = v;
        if (WQ) {
            float f[8];
#pragma unroll
            for (int j = 0; j < 8; ++j) f[j] = bf2f(v[j]);
            float mx = 0.f;
#pragma unroll
            for (int j = 0; j < 8; ++j) mx = fmaxf(mx, fabsf(f[j]));
            mx = fmaxf(mx, __shfl_xor(mx, 1, 64));
            mx = fmaxf(mx, __shfl_xor(mx, 2, 64));
            mx = fmaxf(mx, __shfl_xor(mx, 4, 64));
            mx = fmaxf(mx, __shfl_xor(mx, 8, 64));
            float qi = mx > 0.f ? 127.f / mx : 0.f;
            unsigned w0 = 0, w1 = 0;
#pragma unroll
            for (int j = 0; j < 8; ++j) {
                int u = (int)rintf(f[j] * qi) + 128;
                u = min(max(u, 0), 255);
                if (j < 4) w0 |= (unsigned)u << (8 * j);
                else       w1 |= (unsigned)u << (8 * (j - 4));
            }
            uint2 pk; pk.x = w0; pk.y = w1;
            *(uint2*)&hq[(size_t)g * DD + c] = pk;
            if ((tid & 15) == 0) hsc[g] = mx / 127.f;
        }
    }
    {
        int f = tid & 127;
        int part = tid >> 7;                     // 0 = sum, 1 = sumsq
        int hsel = f >> 6;                       // which col-half wave
        int cw = part * 64 + (f & 63);
        float v = 0.f;
#pragma unroll
        for (int pr = 0; pr < 2; ++pr) v += sstat[(2 * pr + hsel) * 128 + cw];
        partials[blockIdx.x * 256 + tid] = v;
    }
}

// ---------------- BN stats -> affine ----------------
__global__ void k_reduce(const float* __restrict__ partials,
                         const float* __restrict__ gamma, const float* __restrict__ beta,
                         float* __restrict__ aff) {
    int f = blockIdx.x;     // 0..127
    int t = threadIdx.x;    // 256
    float s = 0.f, q = 0.f;
    for (int i = t; i < NBLK; i += 256) {
        s += partials[i * 256 + f];
        q += partials[i * 256 + 128 + f];
    }
    __shared__ float rs[256], rq[256];
    rs[t] = s; rq[t] = q;
    __syncthreads();
    for (int d = 128; d > 0; d >>= 1) {
        if (t < d) { rs[t] += rs[t + d]; rq[t] += rq[t + d]; }
        __syncthreads();
    }
    if (t == 0) {
        float mean = rs[0] / (float)N_NODES;
        float var = rq[0] / (float)N_NODES - mean * mean;
        float a = gamma[f] * rsqrtf(var + EPSV);
        aff[f] = a;
        aff[128 + f] = beta[f] - mean * a;
    }
}

// ---------------- final BN apply: bf16 h2 -> fp32 out ----------------
__global__ void k_apply(const short* __restrict__ hin, const float* __restrict__ aff,
                        float* __restrict__ out) {
    int i = blockIdx.x * 256 + threadIdx.x;  // bf16x8 units
    if (i < N_NODES * DD / 8) {
        bf16x8 v = *(const bf16x8*)(hin + (size_t)i * 8);
        int f = (i * 8) & 127;
        f32x4 a0 = *(const f32x4*)(aff + f);
        f32x4 a1 = *(const f32x4*)(aff + f + 4);
        f32x4 c0 = *(const f32x4*)(aff + 128 + f);
        f32x4 c1 = *(const f32x4*)(aff + 128 + f + 4);
        f32x4 o0, o1;
        o0.x = bf2f(v[0]) * a0.x + c0.x; o0.y = bf2f(v[1]) * a0.y + c0.y;
        o0.z = bf2f(v[2]) * a0.z + c0.z; o0.w = bf2f(v[3]) * a0.w + c0.w;
        o1.x = bf2f(v[4]) * a1.x + c1.x; o1.y = bf2f(v[5]) * a1.y + c1.y;
        o1.z = bf2f(v[6]) * a1.z + c1.z; o1.w = bf2f(v[7]) * a1.w + c1.w;
        *(f32x4*)(out + (size_t)i * 8) = o0;
        *(f32x4*)(out + (size_t)i * 8 + 4) = o1;
    }
}

extern "C" void kernel_launch(void* const* d_in, const int* in_sizes, int n_in,
                              void* d_out, int out_size, void* d_ws, size_t ws_size,
                              hipStream_t stream) {
    const float* x     = (const float*)d_in[0];
    const int*   ei    = (const int*)d_in[1];
    const float* Wl    = (const float*)d_in[2];
    const float* Wr    = (const float*)d_in[3];
    const float* b     = (const float*)d_in[4];
    const float* gamma = (const float*)d_in[5];
    const float* beta  = (const float*)d_in[6];
    float* out = (float*)d_out;

    char* ws = (char*)d_ws;
    int*   off      = (int*)(ws + 0);              // (N+1) ints
    int*   cnt      = (int*)(ws + 400128);         // N ints (count/cursor), then h-scale B
    int*   elist    = (int*)(ws + 800256);         // E ints
    int*   bsums    = (int*)(ws + 4000256);        // 512 ints
    float* partials = (float*)(ws + 4002304);      // NBLK*256 floats (3.2MB)
    float* affine   = (float*)(ws + 7202304);      // 256 floats
    short* wbl      = (short*)(ws + 7203328);      // 128*128 bf16 folded
    short* wbr      = (short*)(ws + 7236096);      // 128*128 bf16 folded
    float* biasb    = (float*)(ws + 7268864);      // 128 floats
    float* biasd    = (float*)(ws + 7269376);      // 128 floats
    short* xb       = (short*)(ws + 7269888);      // N*D bf16, in-place x/h0/h1/h2
    unsigned char* qA = (unsigned char*)(ws + 32869888);  // N*D int8: xq, then h1q
    unsigned char* qB = (unsigned char*)(ws + 45669888);  // N*D int8: h0q
    float* scA = (float*)d_out;                    // N floats scratch in d_out head
                                                   // (x scales, then h1 scales;
                                                   //  overwritten by k_apply)
    float* scB = (float*)cnt;                      // N floats: h0 scales (cnt dead
                                                   //  after k_fill)

    const int* src = ei;
    const int* dst = ei + N_EDGES;

    // CSR build + x -> bf16 + int8/scale
    hipMemsetAsync(cnt, 0, N_NODES * sizeof(int), stream);
    k_setup<<<(N_NODES * DD / 8 + 255) / 256, 256, 0, stream>>>(x, xb, qA, scA, dst, cnt);
    k_scan1<<<NSCAN1, 256, 0, stream>>>(cnt, off, bsums);
    k_scan2<<<1, 512, 0, stream>>>(bsums);
    k_scan3<<<NSCAN1, 256, 0, stream>>>(off, bsums);
    k_fill<<<(N_EDGES + 255) / 256, 256, 0, stream>>>(src, dst, off, cnt, elist);

    // layer 0: root xb(x), gather qA/scA -> h0 in xb + qB/scB, ELU
    k_fold<<<128, 128, 0, stream>>>(Wl, Wr, b, affine, 0, wbl, wbr, biasb, biasd);
    k_sage<true, true><<<NBLK, 256, 0, stream>>>(xb, qA, scA, qB, scB, off, elist,
                                                 wbl, wbr, biasb, biasd, partials);
    k_reduce<<<128, 256, 0, stream>>>(partials, gamma, beta, affine);

    // layer 1: root xb(h0), gather qB/scB -> h1 in xb + qA/scA, ELU
    k_fold<<<128, 128, 0, stream>>>(Wl + DD * DD, Wr + DD * DD, b + DD, affine, 1,
                                    wbl, wbr, biasb, biasd);
    k_sage<true, true><<<NBLK, 256, 0, stream>>>(xb, qB, scB, qA, scA, off, elist,
                                                 wbl, wbr, biasb, biasd, partials);
    k_reduce<<<128, 256, 0, stream>>>(partials, gamma + DD, beta + DD, affine);

    // layer 2: root xb(h1), gather qA/scA -> h2 in xb, no ELU, no quant out
    k_fold<<<128, 128, 0, stream>>>(Wl + 2 * DD * DD, Wr + 2 * DD * DD, b + 2 * DD,
                                    affine, 1, wbl, wbr, biasb, biasd);
    k_sage<false, false><<<NBLK, 256, 0, stream>>>(xb, qA, scA, qB, scB, off, elist,
                                                   wbl, wbr, biasb, biasd, partials);
    k_reduce<<<128, 256, 0, stream>>>(partials, gamma + 2 * DD, beta + 2 * DD, affine);

    // final BN apply: bf16 h2 -> fp32 out (overwrites the scA scratch region)
    k_apply<<<(N_NODES * DD / 8 + 255) / 256, 256, 0, stream>>>(xb, affine, out);
}